// Round 5
// baseline (664.672 us; speedup 1.0000x reference)
//
#include <hip/hip_runtime.h>
#include <math.h>

#define Bn 2
#define Sn 2048
#define En 2048
#define Hn 16
#define HDn 128

typedef __attribute__((ext_vector_type(8))) short short8;
typedef __attribute__((ext_vector_type(4))) float f32x4;
typedef unsigned short u16;
typedef unsigned int u32;

__device__ __forceinline__ float bf2f(u16 x){
  union { u32 u; float f; } v; v.u = ((u32)x) << 16; return v.f;
}
__device__ __forceinline__ u16 f2bf(float f){
  union { float f; u32 u; } v; v.f = f;
  u32 r = v.u + 0x7fff + ((v.u >> 16) & 1);
  return (u16)(r >> 16);
}
__device__ __forceinline__ void gload16(const u16* g, u16* l){
  __builtin_amdgcn_global_load_lds((const __attribute__((address_space(1))) void*)g,
                                   (__attribute__((address_space(3))) void*)l, 16, 0, 0);
}

// ------------- dtype detector: flag=1 if inputs are fp32, 0 if bf16 -------------
__global__ void detect_dtype(const u16* __restrict__ x, int* __restrict__ flag){
  int lane = threadIdx.x;
  int cnt = 0;
  #pragma unroll
  for (int i = 0; i < 4; i++){
    u16 u = x[lane*4 + i];
    int e = (u >> 7) & 0xFF;
    cnt += (e < 96 || e > 159) ? 1 : 0;
  }
  cnt += __shfl_xor(cnt, 1);  cnt += __shfl_xor(cnt, 2);  cnt += __shfl_xor(cnt, 4);
  cnt += __shfl_xor(cnt, 8);  cnt += __shfl_xor(cnt, 16); cnt += __shfl_xor(cnt, 32);
  if (lane == 0) flag[0] = (cnt > 32) ? 1 : 0;
}

// ------------- x -> bf16 workspace copy -------------
__global__ __launch_bounds__(256) void convert_x(const void* __restrict__ xin, u16* __restrict__ xb,
                                                 const int* __restrict__ flag){
  long i8 = ((long)blockIdx.x*256 + threadIdx.x)*8;
  if (flag[0]){
    const float* xf = (const float*)xin;
    float4 a = *(const float4*)(xf + i8);
    float4 b = *(const float4*)(xf + i8 + 4);
    u16 t[8] = {f2bf(a.x),f2bf(a.y),f2bf(a.z),f2bf(a.w),f2bf(b.x),f2bf(b.y),f2bf(b.z),f2bf(b.w)};
    *(uint4*)(xb + i8) = *(uint4*)t;
  } else {
    *(uint4*)(xb + i8) = *(const uint4*)((const u16*)xin + i8);
  }
}

// ------------- transpose 2048x2048 -> bf16: out[n][k] = (bf16)in[k][n] -------------
__global__ __launch_bounds__(256) void transpose2048(const void* __restrict__ in, u16* __restrict__ out,
                                                     const int* __restrict__ flag){
  __shared__ __align__(16) u16 t[64][72];
  int bx = blockIdx.x & 31;
  int by = blockIdx.x >> 5;
  int tid = threadIdx.x;
  int f = flag[0];
  #pragma unroll
  for (int c = tid; c < 512; c += 256){
    int r = c >> 3, col = (c & 7) << 3;
    long base = (long)((by<<6)+r)*2048 + (bx<<6) + col;
    u16 tmp[8];
    if (f){
      const float* pf = (const float*)in + base;
      float4 a = *(const float4*)pf;
      float4 b = *(const float4*)(pf + 4);
      tmp[0]=f2bf(a.x); tmp[1]=f2bf(a.y); tmp[2]=f2bf(a.z); tmp[3]=f2bf(a.w);
      tmp[4]=f2bf(b.x); tmp[5]=f2bf(b.y); tmp[6]=f2bf(b.z); tmp[7]=f2bf(b.w);
    } else {
      *(uint4*)tmp = *(const uint4*)((const u16*)in + base);
    }
    *(uint4*)&t[r][col] = *(uint4*)tmp;
  }
  __syncthreads();
  #pragma unroll
  for (int c = tid; c < 512; c += 256){
    int r = c >> 3, col = (c & 7) << 3;
    u16 tmp[8];
    #pragma unroll
    for (int i = 0; i < 8; i++) tmp[i] = t[col + i][r];
    *(uint4*)(out + (long)((bx<<6)+r)*2048 + (by<<6) + col) = *(uint4*)tmp;
  }
}

// ------------- GEMM: C = A @ Bt^T + bias; XCD supertile swizzle; M=4096,N=2048 -------------
// mode 0: plain, 1: *scale, 2: silu, 3: write transposed C[col][row] (for V^T)
__global__ __launch_bounds__(256) void gemm_bt(const u16* __restrict__ A, const u16* __restrict__ Bt,
                const void* __restrict__ bias, void* __restrict__ C,
                int Mdim, int Ndim, int Kdim, int mode, float scale,
                const int* __restrict__ flag, int outfp){
  __shared__ __align__(16) u16 As[128*32];
  __shared__ __align__(16) u16 Bs[128*32];
  // supertile swizzle: 32x16 tile grid as 4x2 supertiles of 8x8, supertile = XCD (blk&7)
  int blk = blockIdx.x;
  int st = blk & 7, lid = blk >> 3;
  int m0 = ((st >> 1)*8 + (lid & 7)) << 7;
  int n0 = ((st & 1)*8 + (lid >> 3)) << 7;
  int tid = threadIdx.x;
  int w = tid >> 6, lane = tid & 63, l16 = lane & 15, quad = lane >> 4;
  int wm = w & 1, wn = w >> 1;
  int f = flag[0];
  int sr = lane >> 2;
  int sc = (lane & 3) << 3;
  const u16* gA = A  + (long)(m0 + (w<<5) + sr)*Kdim + sc;
  const u16* gB = Bt + (long)(n0 + (w<<5) + sr)*Kdim + sc;
  u16* lA0 = As + (w<<5)*32;  u16* lA1 = lA0 + 512;
  u16* lB0 = Bs + (w<<5)*32;  u16* lB1 = lB0 + 512;
  const long rowskip = (long)16*Kdim;

  f32x4 acc[4][4];
  #pragma unroll
  for (int i = 0; i < 4; i++)
    #pragma unroll
    for (int j = 0; j < 4; j++) acc[i][j] = (f32x4){0.f,0.f,0.f,0.f};

  for (int k0 = 0; k0 < Kdim; k0 += 32){
    __syncthreads();
    gload16(gA + k0,           lA0);
    gload16(gA + k0 + rowskip, lA1);
    gload16(gB + k0,           lB0);
    gload16(gB + k0 + rowskip, lB1);
    __syncthreads();
    short8 af[4], bfr[4];
    #pragma unroll
    for (int mf = 0; mf < 4; mf++) af[mf]  = *(const short8*)&As[(wm*64 + mf*16 + l16)*32 + quad*8];
    #pragma unroll
    for (int nf = 0; nf < 4; nf++) bfr[nf] = *(const short8*)&Bs[(wn*64 + nf*16 + l16)*32 + quad*8];
    #pragma unroll
    for (int mf = 0; mf < 4; mf++)
      #pragma unroll
      for (int nf = 0; nf < 4; nf++)
        acc[mf][nf] = __builtin_amdgcn_mfma_f32_16x16x32_bf16(af[mf], bfr[nf], acc[mf][nf], 0, 0, 0);
  }
  #pragma unroll
  for (int nf = 0; nf < 4; nf++){
    int col = n0 + wn*64 + nf*16 + l16;
    float bv = f ? ((const float*)bias)[col] : bf2f(((const u16*)bias)[col]);
    #pragma unroll
    for (int mf = 0; mf < 4; mf++){
      #pragma unroll
      for (int r = 0; r < 4; r++){
        int row = m0 + wm*64 + mf*16 + quad*4 + r;
        float v = acc[mf][nf][r] + bv;
        if (mode == 1) v *= scale;
        else if (mode == 2) v = v / (1.0f + __expf(-v));
        if (mode == 3){
          ((u16*)C)[(long)col*Mdim + row] = f2bf(v);      // V^T layout [e][tok]
        } else {
          long idx = (long)row*Ndim + col;
          if (outfp && f) ((float*)C)[idx] = v;
          else            ((u16*)C)[idx] = f2bf(v);
        }
      }
    }
  }
}

// ------------- retention + scale + groupnorm + gate, fused -------------
// 2x2 wave tiling (m=32/wave, j-strip=32/wave), per-wave Ss, V^T input,
// bh->XCD clustering, coalesced LDS epilogue.
__global__ __launch_bounds__(256) void retention(const u16* __restrict__ q, const u16* __restrict__ k,
     const u16* __restrict__ vt, const u16* __restrict__ gate, const void* __restrict__ gnw,
     const void* __restrict__ gnb, const void* __restrict__ decay, u16* __restrict__ gated,
     const int* __restrict__ flag){
  __shared__ __align__(16) u16 smem[26624];    // 53248 B -> 3 blocks/CU
  u16* Ks   = smem;           // [64][136]  K tile [j][d]
  u16* Vs   = smem + 8704;    // [128][72]  V^T tile [d][j]
  u16* Ss   = smem + 17920;   // [4][32][40] per-wave P strips
  u16* Obuf = smem + 17920;   // [64][136]  phase-3 (overlaps Ss region)
  float* Xbuf = (float*)smem;            // [64][128] partial-O exchange (overlaps Ks/Vs)
  float* rsX  = (float*)(smem + 16448);  // [64] rowsum exchange

  int blk = blockIdx.x;
  int bh = ((blk & 7) << 2) | ((blk >> 3) & 3);   // same bh -> same XCD
  int it = 31 - (blk >> 5);                       // LPT: longest first
  int b = bh >> 4, h = bh & 15;
  int f = flag[0];
  float dec = f ? ((const float*)decay)[h] : bf2f(((const u16*)decay)[h]);
  int tid = threadIdx.x, w = tid >> 6, lane = tid & 63, l16 = lane & 15, quad = lane >> 4;
  int wm = w & 1, wn = w >> 1;
  u16* Ssw = Ss + w*1280;                         // [32][40]

  // decay factors (all args bounded: |dec|*63 <= 2.01)
  float ei[2][4], ejl[2];
  #pragma unroll
  for (int mf = 0; mf < 2; mf++)
    #pragma unroll
    for (int r = 0; r < 4; r++) ei[mf][r] = __expf(dec * (float)(wm*32 + mf*16 + quad*4 + r));
  #pragma unroll
  for (int nf = 0; nf < 2; nf++) ejl[nf] = __expf(-dec * (float)(wn*32 + nf*16 + l16));

  int i0 = it << 6;
  short8 qf[2][4];
  #pragma unroll
  for (int mf = 0; mf < 2; mf++){
    const u16* qbase = q + (long)(b*Sn + i0 + wm*32 + mf*16 + l16)*En + h*HDn;
    #pragma unroll
    for (int kf = 0; kf < 4; kf++){
      uint4 t = *(const uint4*)(qbase + kf*32 + quad*8);
      qf[mf][kf] = *(short8*)&t;
    }
  }
  f32x4 oacc[2][8];
  #pragma unroll
  for (int mf = 0; mf < 2; mf++)
    #pragma unroll
    for (int nf = 0; nf < 8; nf++) oacc[mf][nf] = (f32x4){0.f,0.f,0.f,0.f};
  float rs[2][4] = {{0.f,0.f,0.f,0.f},{0.f,0.f,0.f,0.f}};

  int njt = it + 1;
  uint4 kreg[4], vreg[4];
  #pragma unroll
  for (int t = 0; t < 4; t++){
    int c = tid + t*256;
    kreg[t] = *(const uint4*)(k  + (long)(b*Sn + (c>>4))*En + h*HDn + ((c&15)<<3));
    vreg[t] = *(const uint4*)(vt + (long)(h*HDn + (c>>3))*4096 + b*Sn + ((c&7)<<3));
  }

  for (int jt = 0; jt < njt; jt++){
    int j0 = jt << 6;
    float etile = __expf(dec * (float)(i0 - j0));
    __syncthreads();
    #pragma unroll
    for (int t = 0; t < 4; t++){
      int c = tid + t*256;
      *(uint4*)&Ks[(c>>4)*136 + ((c&15)<<3)] = kreg[t];
      *(uint4*)&Vs[(c>>3)*72  + ((c&7)<<3)]  = vreg[t];
    }
    __syncthreads();
    if (jt + 1 < njt){
      int jn = j0 + 64;
      #pragma unroll
      for (int t = 0; t < 4; t++){
        int c = tid + t*256;
        kreg[t] = *(const uint4*)(k  + (long)(b*Sn + jn + (c>>4))*En + h*HDn + ((c&15)<<3));
        vreg[t] = *(const uint4*)(vt + (long)(h*HDn + (c>>3))*4096 + b*Sn + jn + ((c&7)<<3));
      }
    }
    // QK: S strip [32 m][32 j] per wave
    int last = (jt == it);
    #pragma unroll
    for (int nf = 0; nf < 2; nf++){
      f32x4 s0 = (f32x4){0.f,0.f,0.f,0.f}, s1 = (f32x4){0.f,0.f,0.f,0.f};
      #pragma unroll
      for (int kf = 0; kf < 4; kf++){
        short8 kfr = *(const short8*)&Ks[(wn*32 + nf*16 + l16)*136 + kf*32 + quad*8];
        s0 = __builtin_amdgcn_mfma_f32_16x16x32_bf16(qf[0][kf], kfr, s0, 0, 0, 0);
        s1 = __builtin_amdgcn_mfma_f32_16x16x32_bf16(qf[1][kf], kfr, s1, 0, 0, 0);
      }
      int rj = wn*32 + nf*16 + l16;
      float ejv = etile * ejl[nf];
      #pragma unroll
      for (int mf = 0; mf < 2; mf++){
        f32x4 sv = mf ? s1 : s0;
        #pragma unroll
        for (int r = 0; r < 4; r++){
          int ri = wm*32 + mf*16 + quad*4 + r;
          float p = sv[r] * ei[mf][r] * ejv;
          if (last) p = (ri >= rj) ? p : 0.0f;
          rs[mf][r] += p;
          Ssw[(mf*16 + quad*4 + r)*40 + nf*16 + l16] = f2bf(p);
        }
      }
    }
    // wave-local LDS drain (per-wave Ss); does NOT drain vmcnt prefetch
    asm volatile("" ::: "memory");
    __builtin_amdgcn_s_waitcnt(0xC07F);
    asm volatile("" ::: "memory");
    // PV partial over this wave's 32-j strip: O[m=32][d=128]
    short8 pa[2];
    #pragma unroll
    for (int mf = 0; mf < 2; mf++) pa[mf] = *(const short8*)&Ssw[(mf*16 + l16)*40 + quad*8];
    #pragma unroll
    for (int nf = 0; nf < 8; nf++){
      short8 vf = *(const short8*)&Vs[(nf*16 + l16)*72 + wn*32 + quad*8];
      oacc[0][nf] = __builtin_amdgcn_mfma_f32_16x16x32_bf16(pa[0], vf, oacc[0][nf], 0, 0, 0);
      oacc[1][nf] = __builtin_amdgcn_mfma_f32_16x16x32_bf16(pa[1], vf, oacc[1][nf], 0, 0, 0);
    }
  }
  // reduce rowsum over this wave's 16 j-lanes
  #pragma unroll
  for (int mf = 0; mf < 2; mf++)
    #pragma unroll
    for (int r = 0; r < 4; r++){
      float x = rs[mf][r];
      x += __shfl_xor(x, 1); x += __shfl_xor(x, 2); x += __shfl_xor(x, 4); x += __shfl_xor(x, 8);
      rs[mf][r] = x;
    }
  __syncthreads();   // S1: all PV reads of Ks/Vs done
  if (wn == 1){      // waves 2,3: export partial O and rowsum
    #pragma unroll
    for (int mf = 0; mf < 2; mf++){
      #pragma unroll
      for (int nf = 0; nf < 8; nf++)
        #pragma unroll
        for (int r = 0; r < 4; r++)
          Xbuf[(wm*32 + mf*16 + quad*4 + r)*128 + nf*16 + l16] = oacc[mf][nf][r];
      if (l16 == 0)
        #pragma unroll
        for (int r = 0; r < 4; r++) rsX[wm*32 + mf*16 + quad*4 + r] = rs[mf][r];
    }
  }
  __syncthreads();   // S2
  if (wn == 0){      // waves 0,1: absorb partner partials, finish rows wm*32..+32
    #pragma unroll
    for (int mf = 0; mf < 2; mf++){
      int rowb = wm*32 + mf*16 + quad*4;
      float rtot[4];
      #pragma unroll
      for (int r = 0; r < 4; r++) rtot[r] = rs[mf][r] + rsX[rowb + r];
      #pragma unroll
      for (int nf = 0; nf < 8; nf++)
        #pragma unroll
        for (int r = 0; r < 4; r++)
          oacc[mf][nf][r] += Xbuf[(rowb + r)*128 + nf*16 + l16];
      // scale + groupnorm stats over 128 ch
      float mu[4], rstd[4];
      #pragma unroll
      for (int r = 0; r < 4; r++){
        float sc = 1.0f / fmaxf(fabsf(rtot[r]), 1.0f);
        #pragma unroll
        for (int nf = 0; nf < 8; nf++) oacc[mf][nf][r] *= sc;
        float s1 = 0.f, s2 = 0.f;
        #pragma unroll
        for (int nf = 0; nf < 8; nf++){ float xv = oacc[mf][nf][r]; s1 += xv; s2 += xv*xv; }
        s1 += __shfl_xor(s1, 1); s1 += __shfl_xor(s1, 2); s1 += __shfl_xor(s1, 4); s1 += __shfl_xor(s1, 8);
        s2 += __shfl_xor(s2, 1); s2 += __shfl_xor(s2, 2); s2 += __shfl_xor(s2, 4); s2 += __shfl_xor(s2, 8);
        float m = s1 * (1.0f/128.0f);
        float var = s2 * (1.0f/128.0f) - m*m;
        mu[r] = m; rstd[r] = rsqrtf(fmaxf(var, 0.0f) + 1e-5f);
      }
      #pragma unroll
      for (int nf = 0; nf < 8; nf++){
        int ch = h*HDn + nf*16 + l16;
        float gwv = f ? ((const float*)gnw)[ch] : bf2f(((const u16*)gnw)[ch]);
        float gbv = f ? ((const float*)gnb)[ch] : bf2f(((const u16*)gnb)[ch]);
        #pragma unroll
        for (int r = 0; r < 4; r++){
          float g = (oacc[mf][nf][r] - mu[r]) * rstd[r] * gwv + gbv;
          Obuf[(rowb + r)*136 + nf*16 + l16] = f2bf(g);
        }
      }
    }
  }
  __syncthreads();   // S3
  // coalesced stream-out: thread -> (row = tid>>2, 32-ch chunk = tid&3)
  {
    int row = tid >> 2, ch0 = (tid & 3) << 5;
    long ga = (long)(b*Sn + i0 + row)*En + h*HDn + ch0;
    #pragma unroll
    for (int cchunk = 0; cchunk < 4; cchunk++){
      uint4 ov = *(const uint4*)&Obuf[row*136 + ch0 + cchunk*8];
      uint4 gv = *(const uint4*)(gate + ga + cchunk*8);
      u16 oa[8], gb_[8], res[8];
      *(uint4*)oa = ov; *(uint4*)gb_ = gv;
      #pragma unroll
      for (int i = 0; i < 8; i++) res[i] = f2bf(bf2f(oa[i]) * bf2f(gb_[i]));
      *(uint4*)(gated + ga + cchunk*8) = *(uint4*)res;
    }
  }
}

extern "C" void kernel_launch(void* const* d_in, const int* in_sizes, int n_in,
                              void* d_out, int out_size, void* d_ws, size_t ws_size,
                              hipStream_t stream){
  const void* x   = d_in[0];
  const void* Wq  = d_in[1];
  const void* bq  = d_in[2];
  const void* Wk  = d_in[3];
  const void* bk  = d_in[4];
  const void* Wv  = d_in[5];
  const void* bv  = d_in[6];
  const void* Wg  = d_in[7];
  const void* bg  = d_in[8];
  const void* Wo  = d_in[9];
  const void* bo  = d_in[10];
  const void* gnw = d_in[11];
  const void* gnb = d_in[12];
  const void* dec = d_in[13];

  u16* base = (u16*)d_ws;
  const size_t WE = (size_t)2048*2048;
  const size_t AE = (size_t)4096*2048;
  u16* xb = base;
  u16* Wt = xb + AE;
  u16* qb = Wt + WE;
  u16* kb = qb + AE;
  u16* vtb = kb + AE;          // V^T [2048 e][4096 tok]
  int* flag = (int*)(vtb + AE);
  u16* gatebuf = (u16*)d_out;
  u16* gtd = qb;

  const float qscale = 0.08838834764831845f; // 128^-0.5

  detect_dtype<<<1, 64, 0, stream>>>((const u16*)x, flag);
  convert_x<<<4096, 256, 0, stream>>>(x, xb, flag);

  transpose2048<<<1024, 256, 0, stream>>>(Wq, Wt, flag);
  gemm_bt<<<512, 256, 0, stream>>>(xb, Wt, bq, qb, 4096, 2048, 2048, 1, qscale, flag, 0);
  transpose2048<<<1024, 256, 0, stream>>>(Wk, Wt, flag);
  gemm_bt<<<512, 256, 0, stream>>>(xb, Wt, bk, kb, 4096, 2048, 2048, 0, 1.0f, flag, 0);
  transpose2048<<<1024, 256, 0, stream>>>(Wv, Wt, flag);
  gemm_bt<<<512, 256, 0, stream>>>(xb, Wt, bv, vtb, 4096, 2048, 2048, 3, 1.0f, flag, 0);
  transpose2048<<<1024, 256, 0, stream>>>(Wg, Wt, flag);
  gemm_bt<<<512, 256, 0, stream>>>(xb, Wt, bg, gatebuf, 4096, 2048, 2048, 2, 1.0f, flag, 0);

  retention<<<1024, 256, 0, stream>>>(qb, kb, vtb, gatebuf, gnw, gnb, dec, gtd, flag);

  transpose2048<<<1024, 256, 0, stream>>>(Wo, Wt, flag);
  gemm_bt<<<512, 256, 0, stream>>>(gtd, Wt, bo, d_out, 4096, 2048, 2048, 0, 1.0f, flag, 1);
}

// Round 6
// 520.272 us; speedup vs baseline: 1.2775x; 1.2775x over previous
//
#include <hip/hip_runtime.h>
#include <math.h>

#define Bn 2
#define Sn 2048
#define En 2048
#define Hn 16
#define HDn 128

typedef __attribute__((ext_vector_type(8))) short short8;
typedef __attribute__((ext_vector_type(4))) float f32x4;
typedef unsigned short u16;
typedef unsigned int u32;

__device__ __forceinline__ float bf2f(u16 x){
  union { u32 u; float f; } v; v.u = ((u32)x) << 16; return v.f;
}
__device__ __forceinline__ u16 f2bf(float f){
  union { float f; u32 u; } v; v.f = f;
  u32 r = v.u + 0x7fff + ((v.u >> 16) & 1);
  return (u16)(r >> 16);
}
__device__ __forceinline__ void gload16(const u16* g, u16* l){
  __builtin_amdgcn_global_load_lds((const __attribute__((address_space(1))) void*)g,
                                   (__attribute__((address_space(3))) void*)l, 16, 0, 0);
}

// ------------- dtype detector: flag=1 if inputs are fp32, 0 if bf16 -------------
__global__ void detect_dtype(const u16* __restrict__ x, int* __restrict__ flag){
  int lane = threadIdx.x;
  int cnt = 0;
  #pragma unroll
  for (int i = 0; i < 4; i++){
    u16 u = x[lane*4 + i];
    int e = (u >> 7) & 0xFF;
    cnt += (e < 96 || e > 159) ? 1 : 0;
  }
  cnt += __shfl_xor(cnt, 1);  cnt += __shfl_xor(cnt, 2);  cnt += __shfl_xor(cnt, 4);
  cnt += __shfl_xor(cnt, 8);  cnt += __shfl_xor(cnt, 16); cnt += __shfl_xor(cnt, 32);
  if (lane == 0) flag[0] = (cnt > 32) ? 1 : 0;
}

// ------------- x -> bf16 workspace copy -------------
__global__ __launch_bounds__(256) void convert_x(const void* __restrict__ xin, u16* __restrict__ xb,
                                                 const int* __restrict__ flag){
  long i8 = ((long)blockIdx.x*256 + threadIdx.x)*8;
  if (flag[0]){
    const float* xf = (const float*)xin;
    float4 a = *(const float4*)(xf + i8);
    float4 b = *(const float4*)(xf + i8 + 4);
    u16 t[8] = {f2bf(a.x),f2bf(a.y),f2bf(a.z),f2bf(a.w),f2bf(b.x),f2bf(b.y),f2bf(b.z),f2bf(b.w)};
    *(uint4*)(xb + i8) = *(uint4*)t;
  } else {
    *(uint4*)(xb + i8) = *(const uint4*)((const u16*)xin + i8);
  }
}

// ------------- transpose 2048x2048 -> bf16: out[n][k] = (bf16)in[k][n] -------------
__global__ __launch_bounds__(256) void transpose2048(const void* __restrict__ in, u16* __restrict__ out,
                                                     const int* __restrict__ flag){
  __shared__ __align__(16) u16 t[64][72];
  int bx = blockIdx.x & 31;
  int by = blockIdx.x >> 5;
  int tid = threadIdx.x;
  int f = flag[0];
  #pragma unroll
  for (int c = tid; c < 512; c += 256){
    int r = c >> 3, col = (c & 7) << 3;
    long base = (long)((by<<6)+r)*2048 + (bx<<6) + col;
    u16 tmp[8];
    if (f){
      const float* pf = (const float*)in + base;
      float4 a = *(const float4*)pf;
      float4 b = *(const float4*)(pf + 4);
      tmp[0]=f2bf(a.x); tmp[1]=f2bf(a.y); tmp[2]=f2bf(a.z); tmp[3]=f2bf(a.w);
      tmp[4]=f2bf(b.x); tmp[5]=f2bf(b.y); tmp[6]=f2bf(b.z); tmp[7]=f2bf(b.w);
    } else {
      *(uint4*)tmp = *(const uint4*)((const u16*)in + base);
    }
    *(uint4*)&t[r][col] = *(uint4*)tmp;
  }
  __syncthreads();
  #pragma unroll
  for (int c = tid; c < 512; c += 256){
    int r = c >> 3, col = (c & 7) << 3;
    u16 tmp[8];
    #pragma unroll
    for (int i = 0; i < 8; i++) tmp[i] = t[col + i][r];
    *(uint4*)(out + (long)((bx<<6)+r)*2048 + (by<<6) + col) = *(uint4*)tmp;
  }
}

// ------------- single GEMM: C = A @ Bt^T + bias; supertile swizzle -------------
// mode 0: plain, 1: *scale, 2: silu. outfp: write float C when flag==fp32.
__global__ __launch_bounds__(256) void gemm_bt(const u16* __restrict__ A, const u16* __restrict__ Bt,
                const void* __restrict__ bias, void* __restrict__ C,
                int Mdim, int Ndim, int Kdim, int mode, float scale,
                const int* __restrict__ flag, int outfp){
  __shared__ __align__(16) u16 As[128*32];
  __shared__ __align__(16) u16 Bs[128*32];
  int blk = blockIdx.x;
  int st = blk & 7, lid = blk >> 3;
  int m0 = ((st >> 1)*8 + (lid & 7)) << 7;
  int n0 = ((st & 1)*8 + (lid >> 3)) << 7;
  int tid = threadIdx.x;
  int w = tid >> 6, lane = tid & 63, l16 = lane & 15, quad = lane >> 4;
  int wm = w & 1, wn = w >> 1;
  int f = flag[0];
  int sr = lane >> 2;
  int sc = (lane & 3) << 3;
  const u16* gA = A  + (long)(m0 + (w<<5) + sr)*Kdim + sc;
  const u16* gB = Bt + (long)(n0 + (w<<5) + sr)*Kdim + sc;
  u16* lA0 = As + (w<<5)*32;  u16* lA1 = lA0 + 512;
  u16* lB0 = Bs + (w<<5)*32;  u16* lB1 = lB0 + 512;
  const long rowskip = (long)16*Kdim;

  f32x4 acc[4][4];
  #pragma unroll
  for (int i = 0; i < 4; i++)
    #pragma unroll
    for (int j = 0; j < 4; j++) acc[i][j] = (f32x4){0.f,0.f,0.f,0.f};

  for (int k0 = 0; k0 < Kdim; k0 += 32){
    __syncthreads();
    gload16(gA + k0,           lA0);
    gload16(gA + k0 + rowskip, lA1);
    gload16(gB + k0,           lB0);
    gload16(gB + k0 + rowskip, lB1);
    __syncthreads();
    short8 af[4], bfr[4];
    #pragma unroll
    for (int mf = 0; mf < 4; mf++) af[mf]  = *(const short8*)&As[(wm*64 + mf*16 + l16)*32 + quad*8];
    #pragma unroll
    for (int nf = 0; nf < 4; nf++) bfr[nf] = *(const short8*)&Bs[(wn*64 + nf*16 + l16)*32 + quad*8];
    #pragma unroll
    for (int mf = 0; mf < 4; mf++)
      #pragma unroll
      for (int nf = 0; nf < 4; nf++)
        acc[mf][nf] = __builtin_amdgcn_mfma_f32_16x16x32_bf16(af[mf], bfr[nf], acc[mf][nf], 0, 0, 0);
  }
  #pragma unroll
  for (int nf = 0; nf < 4; nf++){
    int col = n0 + wn*64 + nf*16 + l16;
    float bv = f ? ((const float*)bias)[col] : bf2f(((const u16*)bias)[col]);
    #pragma unroll
    for (int mf = 0; mf < 4; mf++){
      #pragma unroll
      for (int r = 0; r < 4; r++){
        int row = m0 + wm*64 + mf*16 + quad*4 + r;
        float v = acc[mf][nf][r] + bv;
        if (mode == 1) v *= scale;
        else if (mode == 2) v = v / (1.0f + __expf(-v));
        long idx = (long)row*Ndim + col;
        if (outfp && f) ((float*)C)[idx] = v;
        else            ((u16*)C)[idx] = f2bf(v);
      }
    }
  }
}

// ------------- fused 4-weight GEMM: {q,k,v,gate} = x @ {Wq,Wk,Wv,Wg} + bias -------------
// grid 2048 = 8 XCD x (4 m-tiles x 16 n x 4 w). Per XCD: A panels 2MB L2-resident;
// 4 consecutive blocks share one B panel. Cuts beyond-L2 traffic ~2GB -> ~270MB.
__global__ __launch_bounds__(256) void gemm4(const u16* __restrict__ A, const u16* __restrict__ Wt4,
                const void* __restrict__ bq_, const void* __restrict__ bk_,
                const void* __restrict__ bv_, const void* __restrict__ bg_,
                u16* __restrict__ qo, u16* __restrict__ ko, u16* __restrict__ vo, u16* __restrict__ go,
                const int* __restrict__ flag, float qscale){
  __shared__ __align__(16) u16 As[128*32];
  __shared__ __align__(16) u16 Bs[128*32];
  const int Kdim = 2048, Ndim = 2048;
  const size_t WE = (size_t)2048*2048;
  int blk = blockIdx.x;
  int xcd = blk & 7, lid = blk >> 3;            // lid 0..255 sequential per XCD
  int m0 = ((xcd << 2) | (lid & 3)) << 7;       // 4 m-tiles per XCD (A 2MB resident)
  int n0 = ((lid >> 2) & 15) << 7;
  int wsel = lid >> 6;                          // 0:q 1:k 2:v 3:gate
  const u16* Bt = Wt4 + WE*(size_t)wsel;
  const void* bias = (wsel==0) ? bq_ : (wsel==1) ? bk_ : (wsel==2) ? bv_ : bg_;
  u16* C = (wsel==0) ? qo : (wsel==1) ? ko : (wsel==2) ? vo : go;
  int tid = threadIdx.x;
  int w = tid >> 6, lane = tid & 63, l16 = lane & 15, quad = lane >> 4;
  int wm = w & 1, wn = w >> 1;
  int f = flag[0];
  int sr = lane >> 2;
  int sc = (lane & 3) << 3;
  const u16* gA = A  + (long)(m0 + (w<<5) + sr)*Kdim + sc;
  const u16* gB = Bt + (long)(n0 + (w<<5) + sr)*Kdim + sc;
  u16* lA0 = As + (w<<5)*32;  u16* lA1 = lA0 + 512;
  u16* lB0 = Bs + (w<<5)*32;  u16* lB1 = lB0 + 512;
  const long rowskip = (long)16*Kdim;

  f32x4 acc[4][4];
  #pragma unroll
  for (int i = 0; i < 4; i++)
    #pragma unroll
    for (int j = 0; j < 4; j++) acc[i][j] = (f32x4){0.f,0.f,0.f,0.f};

  for (int k0 = 0; k0 < Kdim; k0 += 32){
    __syncthreads();
    gload16(gA + k0,           lA0);
    gload16(gA + k0 + rowskip, lA1);
    gload16(gB + k0,           lB0);
    gload16(gB + k0 + rowskip, lB1);
    __syncthreads();
    short8 af[4], bfr[4];
    #pragma unroll
    for (int mf = 0; mf < 4; mf++) af[mf]  = *(const short8*)&As[(wm*64 + mf*16 + l16)*32 + quad*8];
    #pragma unroll
    for (int nf = 0; nf < 4; nf++) bfr[nf] = *(const short8*)&Bs[(wn*64 + nf*16 + l16)*32 + quad*8];
    #pragma unroll
    for (int mf = 0; mf < 4; mf++)
      #pragma unroll
      for (int nf = 0; nf < 4; nf++)
        acc[mf][nf] = __builtin_amdgcn_mfma_f32_16x16x32_bf16(af[mf], bfr[nf], acc[mf][nf], 0, 0, 0);
  }
  #pragma unroll
  for (int nf = 0; nf < 4; nf++){
    int col = n0 + wn*64 + nf*16 + l16;
    float bv = f ? ((const float*)bias)[col] : bf2f(((const u16*)bias)[col]);
    #pragma unroll
    for (int mf = 0; mf < 4; mf++){
      #pragma unroll
      for (int r = 0; r < 4; r++){
        int row = m0 + wm*64 + mf*16 + quad*4 + r;
        float v = acc[mf][nf][r] + bv;
        if (wsel == 0) v *= qscale;
        else if (wsel == 3) v = v / (1.0f + __expf(-v));
        C[(long)row*Ndim + col] = f2bf(v);
      }
    }
  }
}

// ------------- retention + scale + groupnorm + gate, fused (R4-proven version) -------------
__global__ __launch_bounds__(256) void retention(const u16* __restrict__ q, const u16* __restrict__ k,
     const u16* __restrict__ v, const u16* __restrict__ gate, const void* __restrict__ gnw,
     const void* __restrict__ gnb, const void* __restrict__ decay, u16* __restrict__ gated,
     const int* __restrict__ flag){
  __shared__ __align__(16) u16 Ks[64][136];
  __shared__ __align__(16) u16 Vt[128][72];
  __shared__ __align__(16) u16 Ss[4][16][72];
  int bh = blockIdx.x & 31;
  int it = 31 - (blockIdx.x >> 5);      // LPT: longest first
  int b = bh >> 4, h = bh & 15;
  int f = flag[0];
  float dec = f ? ((const float*)decay)[h] : bf2f(((const u16*)decay)[h]);
  int tid = threadIdx.x, w = tid >> 6, lane = tid & 63, l16 = lane & 15, quad = lane >> 4;

  float gw8[8], gb8[8];
  #pragma unroll
  for (int nf = 0; nf < 8; nf++){
    int ch = h*HDn + nf*16 + l16;
    gw8[nf] = f ? ((const float*)gnw)[ch] : bf2f(((const u16*)gnw)[ch]);
    gb8[nf] = f ? ((const float*)gnb)[ch] : bf2f(((const u16*)gnb)[ch]);
  }
  float ei4[4], ejl[4];
  #pragma unroll
  for (int r = 0; r < 4; r++) ei4[r] = __expf(dec * (float)(w*16 + quad*4 + r));
  #pragma unroll
  for (int nf = 0; nf < 4; nf++) ejl[nf] = __expf(-dec * (float)(nf*16 + l16));

  int i0 = it << 6;
  short8 qf[4];
  {
    int qrow = i0 + w*16 + l16;
    const u16* qbase = q + (long)(b*Sn + qrow)*En + h*HDn;
    #pragma unroll
    for (int kf = 0; kf < 4; kf++){
      uint4 t = *(const uint4*)(qbase + kf*32 + quad*8);
      qf[kf] = *(short8*)&t;
    }
  }
  f32x4 oacc[8];
  #pragma unroll
  for (int i = 0; i < 8; i++) oacc[i] = (f32x4){0.f,0.f,0.f,0.f};
  float rs[4] = {0.f,0.f,0.f,0.f};

  int njt = it + 1;
  uint4 kreg[4], vreg[4];
  #pragma unroll
  for (int t = 0; t < 4; t++){
    int c = tid + t*256;
    int jr = c >> 4, dc = (c & 15) << 3;
    kreg[t] = *(const uint4*)(k + (long)(b*Sn + jr)*En + h*HDn + dc);
    int jr2 = c & 63, dc2 = (c >> 6) << 3;
    vreg[t] = *(const uint4*)(v + (long)(b*Sn + jr2)*En + h*HDn + dc2);
  }

  for (int jt = 0; jt < njt; jt++){
    int j0 = jt << 6;
    float etile = __expf(dec * (float)(i0 - j0));
    float em[4];
    #pragma unroll
    for (int r = 0; r < 4; r++) em[r] = etile * ei4[r];
    __syncthreads();
    #pragma unroll
    for (int t = 0; t < 4; t++){
      int c = tid + t*256;
      int jr = c >> 4, dc = (c & 15) << 3;
      *(uint4*)&Ks[jr][dc] = kreg[t];
      int jr2 = c & 63, dc2 = (c >> 6) << 3;
      u16 tmp[8]; *(uint4*)tmp = vreg[t];
      #pragma unroll
      for (int i = 0; i < 8; i++) Vt[dc2 + i][jr2] = tmp[i];
    }
    __syncthreads();
    if (jt + 1 < njt){
      int jn = j0 + 64;
      #pragma unroll
      for (int t = 0; t < 4; t++){
        int c = tid + t*256;
        int jr = c >> 4, dc = (c & 15) << 3;
        kreg[t] = *(const uint4*)(k + (long)(b*Sn + jn + jr)*En + h*HDn + dc);
        int jr2 = c & 63, dc2 = (c >> 6) << 3;
        vreg[t] = *(const uint4*)(v + (long)(b*Sn + jn + jr2)*En + h*HDn + dc2);
      }
    }
    #pragma unroll
    for (int nf = 0; nf < 4; nf++){
      f32x4 s = (f32x4){0.f,0.f,0.f,0.f};
      #pragma unroll
      for (int kf = 0; kf < 4; kf++){
        short8 kfr = *(const short8*)&Ks[nf*16 + l16][kf*32 + quad*8];
        s = __builtin_amdgcn_mfma_f32_16x16x32_bf16(qf[kf], kfr, s, 0, 0, 0);
      }
      int j = j0 + nf*16 + l16;
      #pragma unroll
      for (int r = 0; r < 4; r++){
        int i = i0 + w*16 + quad*4 + r;
        float p = s[r] * em[r] * ejl[nf];
        p = (i >= j) ? p : 0.0f;
        rs[r] += p;
        Ss[w][quad*4 + r][nf*16 + l16] = f2bf(p);
      }
    }
    asm volatile("" ::: "memory");
    __builtin_amdgcn_s_waitcnt(0xC07F);   // lgkmcnt(0), keeps vmcnt prefetch alive
    asm volatile("" ::: "memory");
    #pragma unroll
    for (int kf = 0; kf < 2; kf++){
      short8 pa = *(const short8*)&Ss[w][l16][kf*32 + quad*8];
      #pragma unroll
      for (int nf = 0; nf < 8; nf++){
        short8 vf = *(const short8*)&Vt[nf*16 + l16][kf*32 + quad*8];
        oacc[nf] = __builtin_amdgcn_mfma_f32_16x16x32_bf16(pa, vf, oacc[nf], 0, 0, 0);
      }
    }
  }
  #pragma unroll
  for (int r = 0; r < 4; r++){
    float x = rs[r];
    x += __shfl_xor(x, 1); x += __shfl_xor(x, 2); x += __shfl_xor(x, 4); x += __shfl_xor(x, 8);
    float sc = 1.0f / fmaxf(fabsf(x), 1.0f);
    #pragma unroll
    for (int nf = 0; nf < 8; nf++) oacc[nf][r] *= sc;
  }
  float mu[4], rstd[4];
  #pragma unroll
  for (int r = 0; r < 4; r++){
    float s1 = 0.f, s2 = 0.f;
    #pragma unroll
    for (int nf = 0; nf < 8; nf++){ float xv = oacc[nf][r]; s1 += xv; s2 += xv*xv; }
    s1 += __shfl_xor(s1, 1); s1 += __shfl_xor(s1, 2); s1 += __shfl_xor(s1, 4); s1 += __shfl_xor(s1, 8);
    s2 += __shfl_xor(s2, 1); s2 += __shfl_xor(s2, 2); s2 += __shfl_xor(s2, 4); s2 += __shfl_xor(s2, 8);
    float m = s1 * (1.0f/128.0f);
    float var = s2 * (1.0f/128.0f) - m*m;
    mu[r] = m; rstd[r] = rsqrtf(fmaxf(var, 0.0f) + 1e-5f);
  }
  #pragma unroll
  for (int nf = 0; nf < 8; nf++){
    int ch = h*HDn + nf*16 + l16;
    #pragma unroll
    for (int r = 0; r < 4; r++){
      int row = i0 + w*16 + quad*4 + r;
      long ga = (long)(b*Sn + row)*En + ch;
      float g = (oacc[nf][r] - mu[r]) * rstd[r] * gw8[nf] + gb8[nf];
      float gt = bf2f(gate[ga]);
      gated[ga] = f2bf(gt * g);
    }
  }
}

extern "C" void kernel_launch(void* const* d_in, const int* in_sizes, int n_in,
                              void* d_out, int out_size, void* d_ws, size_t ws_size,
                              hipStream_t stream){
  const void* x   = d_in[0];
  const void* Wq  = d_in[1];
  const void* bq  = d_in[2];
  const void* Wk  = d_in[3];
  const void* bk  = d_in[4];
  const void* Wv  = d_in[5];
  const void* bv  = d_in[6];
  const void* Wg  = d_in[7];
  const void* bg  = d_in[8];
  const void* Wo  = d_in[9];
  const void* bo  = d_in[10];
  const void* gnw = d_in[11];
  const void* gnb = d_in[12];
  const void* dec = d_in[13];

  u16* base = (u16*)d_ws;
  const size_t WE = (size_t)2048*2048;
  const size_t AE = (size_t)4096*2048;
  const float qscale = 0.08838834764831845f; // 128^-0.5
  u16* gatebuf = (u16*)d_out;   // gate scratch inside d_out until final GEMM overwrites

  const size_t fused_bytes = (AE*4 + WE*4)*2 + 64;   // xb + 4*Wt + q/k/v

  if (ws_size >= fused_bytes){
    // ---- fused path: all 4 input GEMMs in one dispatch ----
    u16* xb  = base;
    u16* Wt4 = xb + AE;
    u16* qb  = Wt4 + 4*WE;
    u16* kb  = qb + AE;
    u16* vb  = kb + AE;
    int* flag = (int*)(vb + AE);
    u16* gtd = qb;

    detect_dtype<<<1, 64, 0, stream>>>((const u16*)x, flag);
    convert_x<<<4096, 256, 0, stream>>>(x, xb, flag);
    transpose2048<<<1024, 256, 0, stream>>>(Wq, Wt4,        flag);
    transpose2048<<<1024, 256, 0, stream>>>(Wk, Wt4 + WE,   flag);
    transpose2048<<<1024, 256, 0, stream>>>(Wv, Wt4 + 2*WE, flag);
    transpose2048<<<1024, 256, 0, stream>>>(Wg, Wt4 + 3*WE, flag);

    gemm4<<<2048, 256, 0, stream>>>(xb, Wt4, bq, bk, bv, bg, qb, kb, vb, gatebuf, flag, qscale);

    retention<<<1024, 256, 0, stream>>>(qb, kb, vb, gatebuf, gnw, gnb, dec, gtd, flag);

    transpose2048<<<1024, 256, 0, stream>>>(Wo, Wt4, flag);
    gemm_bt<<<512, 256, 0, stream>>>(gtd, Wt4, bo, d_out, 4096, 2048, 2048, 0, 1.0f, flag, 1);
  } else {
    // ---- serial fallback (R4 pipeline) ----
    u16* xb = base;
    u16* Wt = xb + AE;
    u16* qb = Wt + WE;
    u16* kb = qb + AE;
    u16* vb = kb + AE;
    int* flag = (int*)(vb + AE);
    u16* gtd = qb;

    detect_dtype<<<1, 64, 0, stream>>>((const u16*)x, flag);
    convert_x<<<4096, 256, 0, stream>>>(x, xb, flag);

    transpose2048<<<1024, 256, 0, stream>>>(Wq, Wt, flag);
    gemm_bt<<<512, 256, 0, stream>>>(xb, Wt, bq, qb, 4096, 2048, 2048, 1, qscale, flag, 0);
    transpose2048<<<1024, 256, 0, stream>>>(Wk, Wt, flag);
    gemm_bt<<<512, 256, 0, stream>>>(xb, Wt, bk, kb, 4096, 2048, 2048, 0, 1.0f, flag, 0);
    transpose2048<<<1024, 256, 0, stream>>>(Wv, Wt, flag);
    gemm_bt<<<512, 256, 0, stream>>>(xb, Wt, bv, vb, 4096, 2048, 2048, 0, 1.0f, flag, 0);
    transpose2048<<<1024, 256, 0, stream>>>(Wg, Wt, flag);
    gemm_bt<<<512, 256, 0, stream>>>(xb, Wt, bg, gatebuf, 4096, 2048, 2048, 2, 1.0f, flag, 0);

    retention<<<1024, 256, 0, stream>>>(qb, kb, vb, gatebuf, gnw, gnb, dec, gtd, flag);

    transpose2048<<<1024, 256, 0, stream>>>(Wo, Wt, flag);
    gemm_bt<<<512, 256, 0, stream>>>(gtd, Wt, bo, d_out, 4096, 2048, 2048, 0, 1.0f, flag, 1);
  }
}